// Round 13
// baseline (57.769 us; speedup 1.0000x reference)
//
#include <hip/hip_runtime.h>

#define AS1 __attribute__((address_space(1)))
#define AS3 __attribute__((address_space(3)))

typedef unsigned short u16;
typedef _Float16 f16;
typedef __bf16 bf16x8 __attribute__((ext_vector_type(8)));
typedef float f32x4 __attribute__((ext_vector_type(4)));
typedef _Float16 f16x8 __attribute__((ext_vector_type(8)));
typedef unsigned short u16x8 __attribute__((ext_vector_type(8)));

// DIAGNOSTIC: r8 structure verbatim; ONLY the gemm runs 5 identical passes
// (idempotent) so its per-dispatch counters appear in rocprof top-5.
//   true_gemm = (total - 25.1)/4 ; gemm row's counters = current schedule.
//
// ws layout (20 MB):
//   A: [4][512][1024]  bf16(u16) @ 0      (4 MB)
//   W: [4][1024][1024] bf16(u16) @ 4 MB   (8 MB)
//   P: [8][512][1024]  f16       @ 12 MB  (8 MB)

__device__ __forceinline__ u16 f2bf(float f) {
    union { float f; unsigned int u; } v;
    v.f = f;
    unsigned int u = v.u;
    u += 0x7fffu + ((u >> 16) & 1u);   // RNE
    return (u16)(u >> 16);
}

// r8 prep verbatim.
__global__ __launch_bounds__(256) void prep_kernel(
    const float* __restrict__ x,
    const float* __restrict__ cp0, const float* __restrict__ cp1,
    const float* __restrict__ cp2, const float* __restrict__ cp3,
    u16* __restrict__ A, u16* __restrict__ W)
{
    const int bid = blockIdx.x;
    const int tid = threadIdx.x;
    if (bid < 512) {
        const int idx = (bid * 256 + tid) * 8;
        const float* cps[4] = {cp0, cp1, cp2, cp3};
        #pragma unroll
        for (int seg = 0; seg < 4; ++seg) {
            float4 v0 = *(const float4*)(cps[seg] + idx);
            float4 v1 = *(const float4*)(cps[seg] + idx + 4);
            u16x8 o;
            o[0] = f2bf(v0.x); o[1] = f2bf(v0.y); o[2] = f2bf(v0.z); o[3] = f2bf(v0.w);
            o[4] = f2bf(v1.x); o[5] = f2bf(v1.y); o[6] = f2bf(v1.z); o[7] = f2bf(v1.w);
            *(u16x8*)(W + seg * 1048576 + idx) = o;
        }
    } else {
        const int idx = ((bid - 512) * 256 + tid) * 8;
        float4 v0 = *(const float4*)(x + idx);
        float4 v1 = *(const float4*)(x + idx + 4);
        float vv[8] = {v0.x, v0.y, v0.z, v0.w, v1.x, v1.y, v1.z, v1.w};
        u16 q[4][8];
        #pragma unroll
        for (int j = 0; j < 8; ++j) {
            float xx = vv[j];
            float t = fminf(fabsf(xx), 1.0f);
            float s = 1.0f - t;
            q[0][j] = f2bf(s * s * s * xx);
            q[1][j] = f2bf(3.0f * s * s * t * xx);
            q[2][j] = f2bf(3.0f * s * t * t * xx);
            q[3][j] = f2bf(t * t * t * xx);
        }
        #pragma unroll
        for (int seg = 0; seg < 4; ++seg) {
            u16x8 o;
            #pragma unroll
            for (int j = 0; j < 8; ++j) o[j] = q[seg][j];
            *(u16x8*)(A + seg * 524288 + idx) = o;
        }
    }
}

__device__ __forceinline__ void load16(const u16* g, u16* l) {
    __builtin_amdgcn_global_load_lds((const AS1 unsigned int*)g,
                                     (AS3 unsigned int*)l, 16, 0, 0);
}

// r8 gemm with x5 pass loop (diagnostic amplification only).
__global__ __launch_bounds__(512) void gemm_kernel(
    const u16* __restrict__ A, const u16* __restrict__ W,
    f16* __restrict__ P)
{
    __shared__ u16 lsA[2][128 * 128];
    __shared__ u16 lsB[2][128 * 128];

    const int tid  = threadIdx.x;
    const int lane = tid & 63;
    const int wid  = tid >> 6;

    const int bid  = blockIdx.x;
    const int nb   = bid & 7;
    const int mb   = (bid >> 3) & 3;
    const int kz   = bid >> 5;
    const int seg  = kz >> 1;
    const int kbase = (kz & 1) * 512;
    const int brow = mb * 128;
    const int bcol = nb * 128;

    const u16* Ag = A + seg * 524288  + brow * 1024 + kbase;
    const u16* Wg = W + seg * 1048576 + bcol * 1024 + kbase;

    int goff[4], loff[4];
    #pragma unroll
    for (int j = 0; j < 4; ++j) {
        const int c   = tid + j * 512;
        const int row = c >> 4;
        goff[j] = row * 1024 + ((c & 15) ^ (row & 15)) * 8;
        loff[j] = c * 8;
    }

    const int wr = (wid >> 2) * 64;
    const int wc = (wid & 3) * 32;
    const int fr = lane & 15;
    const int q  = lane >> 4;
    int ofs[4];
    #pragma unroll
    for (int kk = 0; kk < 4; ++kk)
        ofs[kk] = ((kk * 4 + q) ^ fr) * 16;

    #pragma unroll 1
    for (int pass = 0; pass < 5; ++pass) {
        f32x4 acc[4][2] = {};

        #pragma unroll
        for (int j = 0; j < 4; ++j) {
            load16(Ag + goff[j], &lsA[0][loff[j]]);
            load16(Wg + goff[j], &lsB[0][loff[j]]);
        }

        #pragma unroll
        for (int kt = 0; kt < 4; ++kt) {
            const int buf = kt & 1;
            if (kt < 3) {
                const int k0 = (kt + 1) * 128;
                #pragma unroll
                for (int j = 0; j < 4; ++j) {
                    load16(Ag + k0 + goff[j], &lsA[buf ^ 1][loff[j]]);
                    load16(Wg + k0 + goff[j], &lsB[buf ^ 1][loff[j]]);
                }
                asm volatile("s_waitcnt vmcnt(8)" ::: "memory");
            } else {
                asm volatile("s_waitcnt vmcnt(0)" ::: "memory");
            }
            __builtin_amdgcn_s_barrier();
            __builtin_amdgcn_sched_barrier(0);     // rule #18

            const char* bA = (const char*)lsA[buf];
            const char* bB = (const char*)lsB[buf];
            #pragma unroll
            for (int kk = 0; kk < 4; ++kk) {
                bf16x8 a[4], b[2];
                #pragma unroll
                for (int m = 0; m < 4; ++m)
                    a[m] = *(const bf16x8*)(bA + (wr + m * 16 + fr) * 256 + ofs[kk]);
                #pragma unroll
                for (int n = 0; n < 2; ++n)
                    b[n] = *(const bf16x8*)(bB + (wc + n * 16 + fr) * 256 + ofs[kk]);
                #pragma unroll
                for (int m = 0; m < 4; ++m)
                    #pragma unroll
                    for (int n = 0; n < 2; ++n)
                        acc[m][n] = __builtin_amdgcn_mfma_f32_16x16x32_bf16(
                            a[m], b[n], acc[m][n], 0, 0, 0);
            }
            __builtin_amdgcn_s_barrier();
            __builtin_amdgcn_sched_barrier(0);
        }

        f16* Pk = P + kz * 524288;
        const int cr0 = brow + wr + q * 4;
        const int cc0 = bcol + wc + fr;
        #pragma unroll
        for (int m = 0; m < 4; ++m)
            #pragma unroll
            for (int n = 0; n < 2; ++n)
                #pragma unroll
                for (int j = 0; j < 4; ++j)
                    Pk[(cr0 + m * 16 + j) * 1024 + cc0 + n * 16] = (f16)acc[m][n][j];

        asm volatile("" ::: "memory");   // force full re-execution per pass
        __syncthreads();                 // stores visible before restage
    }
}

// r8 reduce verbatim.
__global__ __launch_bounds__(256) void reduce_kernel(
    const f16* __restrict__ P, float* __restrict__ out)
{
    const int idx = (blockIdx.x * 256 + threadIdx.x) * 8;
    float s[8] = {};
    #pragma unroll
    for (int z = 0; z < 8; ++z) {
        f16x8 v = *(const f16x8*)(P + z * 524288 + idx);
        #pragma unroll
        for (int e = 0; e < 8; ++e) s[e] += (float)v[e];
    }
    float4 o0, o1;
    o0.x = s[0]; o0.y = s[1]; o0.z = s[2]; o0.w = s[3];
    o1.x = s[4]; o1.y = s[5]; o1.z = s[6]; o1.w = s[7];
    *(float4*)(out + idx)     = o0;
    *(float4*)(out + idx + 4) = o1;
}

extern "C" void kernel_launch(void* const* d_in, const int* in_sizes, int n_in,
                              void* d_out, int out_size, void* d_ws, size_t ws_size,
                              hipStream_t stream)
{
    const float* x   = (const float*)d_in[0];
    const float* cp0 = (const float*)d_in[1];
    const float* cp1 = (const float*)d_in[2];
    const float* cp2 = (const float*)d_in[3];
    const float* cp3 = (const float*)d_in[4];

    u16*   A   = (u16*)d_ws;
    u16*   Wb  = (u16*)((char*)d_ws + (4u << 20));
    f16*   P   = (f16*)((char*)d_ws + (12u << 20));
    float* out = (float*)d_out;

    prep_kernel<<<768, 256, 0, stream>>>(x, cp0, cp1, cp2, cp3, A, Wb);
    gemm_kernel<<<256, 512, 0, stream>>>(A, Wb, P);
    reduce_kernel<<<256, 256, 0, stream>>>(P, out);
}

// Round 14
// 24.842 us; speedup vs baseline: 2.3255x; 2.3255x over previous
//
#include <hip/hip_runtime.h>

#define AS1 __attribute__((address_space(1)))
#define AS3 __attribute__((address_space(3)))

typedef unsigned short u16;
typedef _Float16 f16;
typedef __bf16 bf16x8 __attribute__((ext_vector_type(8)));
typedef float f32x4 __attribute__((ext_vector_type(4)));
typedef _Float16 f16x8 __attribute__((ext_vector_type(8)));
typedef unsigned short u16x8 __attribute__((ext_vector_type(8)));

// ws layout (20 MB):
//   A: [4][512][1024]  bf16(u16) @ 0      (4 MB)   A[seg][b][i] = b_seg(x[b][i])
//   W: [4][1024][1024] bf16(u16) @ 4 MB   (8 MB)   W[seg][o][i] = bf16(cp_seg[o][i])
//   P: [8][512][1024]  f16       @ 12 MB  (8 MB)   split-K partials (f16)

__device__ __forceinline__ u16 bf(float f) {
    union { __bf16 h; u16 u; } c;
    c.h = (__bf16)f;               // RNE, compiler-optimal cvt (m240)
    return c.u;
}

// Streaming-clean prep: one block = one contiguous chunk of ONE source stream.
// bid<512: W. seg=bid>>7, 32KB f32 read -> 16KB bf16 write, 4 iters.
// bid>=512 (128 blocks): A. 1 read stream -> 4 seg write streams (6 MB total).
__global__ __launch_bounds__(256) void prep_kernel(
    const float* __restrict__ x,
    const float* __restrict__ cp0, const float* __restrict__ cp1,
    const float* __restrict__ cp2, const float* __restrict__ cp3,
    u16* __restrict__ A, u16* __restrict__ W)
{
    const int bid = blockIdx.x;
    const int tid = threadIdx.x;
    if (bid < 512) {
        const int seg  = bid >> 7;                 // 0..3
        const int base = (bid & 127) * 8192;       // elem offset within cp[seg]
        const float* cps[4] = {cp0, cp1, cp2, cp3};
        const float* src = cps[seg] + base;
        u16* dst = W + seg * 1048576 + base;
        #pragma unroll
        for (int it = 0; it < 4; ++it) {
            const int e = it * 2048 + tid * 8;
            float4 v0 = *(const float4*)(src + e);
            float4 v1 = *(const float4*)(src + e + 4);
            u16x8 o;
            o[0] = bf(v0.x); o[1] = bf(v0.y); o[2] = bf(v0.z); o[3] = bf(v0.w);
            o[4] = bf(v1.x); o[5] = bf(v1.y); o[6] = bf(v1.z); o[7] = bf(v1.w);
            *(u16x8*)(dst + e) = o;
        }
    } else {
        const int base = (bid - 512) * 4096;       // x elems, 128 blocks x 4096
        #pragma unroll
        for (int it = 0; it < 2; ++it) {
            const int idx = base + it * 2048 + tid * 8;
            float4 v0 = *(const float4*)(x + idx);
            float4 v1 = *(const float4*)(x + idx + 4);
            float vv[8] = {v0.x, v0.y, v0.z, v0.w, v1.x, v1.y, v1.z, v1.w};
            u16 q[4][8];
            #pragma unroll
            for (int j = 0; j < 8; ++j) {
                float xx = vv[j];
                float t = fminf(fabsf(xx), 1.0f);
                float s = 1.0f - t;
                q[0][j] = bf(s * s * s * xx);
                q[1][j] = bf(3.0f * s * s * t * xx);
                q[2][j] = bf(3.0f * s * t * t * xx);
                q[3][j] = bf(t * t * t * xx);
            }
            #pragma unroll
            for (int seg = 0; seg < 4; ++seg) {
                u16x8 o;
                #pragma unroll
                for (int j = 0; j < 8; ++j) o[j] = q[seg][j];
                *(u16x8*)(A + seg * 524288 + idx) = o;
            }
        }
    }
}

__device__ __forceinline__ void load16(const u16* g, u16* l) {
    __builtin_amdgcn_global_load_lds((const AS1 unsigned int*)g,
                                     (AS3 unsigned int*)l, 16, 0, 0);
}

// r8 gemm + 2x2 XCD grouping: bid%8 selects a (2 mb x 2 nb) tile-group whose
// per-XCD working set (2MB A-half + 2MB W-pair = 4MB) fits one XCD L2.
// 128x128 tile, BK=128 (4 k-steps), split-K=8, 512 threads (8 waves of 64x32),
// counted-vmcnt pipeline (never vmcnt(0) in loop), XOR-swizzled LDS.
__global__ __launch_bounds__(512) void gemm_kernel(
    const u16* __restrict__ A, const u16* __restrict__ W,
    f16* __restrict__ P)
{
    __shared__ u16 lsA[2][128 * 128];
    __shared__ u16 lsB[2][128 * 128];

    const int tid  = threadIdx.x;
    const int lane = tid & 63;
    const int wid  = tid >> 6;

    const int bid  = blockIdx.x;          // 0..255
    const int grp  = bid & 7;             // XCD group = (mb>>1)*4 + (nb>>1)
    const int sub  = bid >> 3;            // 0..31 within group
    const int mb   = (grp >> 2) * 2 + (sub & 1);
    const int nb   = (grp & 3) * 2 + ((sub >> 1) & 1);
    const int kz   = sub >> 2;            // 0..7
    const int seg  = kz >> 1;
    const int kbase = (kz & 1) * 512;
    const int brow = mb * 128;
    const int bcol = nb * 128;

    const u16* Ag = A + seg * 524288  + brow * 1024 + kbase;
    const u16* Wg = W + seg * 1048576 + bcol * 1024 + kbase;

    int goff[4], loff[4];
    #pragma unroll
    for (int j = 0; j < 4; ++j) {
        const int c   = tid + j * 512;
        const int row = c >> 4;
        goff[j] = row * 1024 + ((c & 15) ^ (row & 15)) * 8;
        loff[j] = c * 8;
    }

    const int wr = (wid >> 2) * 64;
    const int wc = (wid & 3) * 32;
    const int fr = lane & 15;
    const int q  = lane >> 4;
    int ofs[4];
    #pragma unroll
    for (int kk = 0; kk < 4; ++kk)
        ofs[kk] = ((kk * 4 + q) ^ fr) * 16;

    f32x4 acc[4][2] = {};

    #pragma unroll
    for (int j = 0; j < 4; ++j) {
        load16(Ag + goff[j], &lsA[0][loff[j]]);
        load16(Wg + goff[j], &lsB[0][loff[j]]);
    }

    #pragma unroll
    for (int kt = 0; kt < 4; ++kt) {
        const int buf = kt & 1;
        if (kt < 3) {
            const int k0 = (kt + 1) * 128;
            #pragma unroll
            for (int j = 0; j < 4; ++j) {
                load16(Ag + k0 + goff[j], &lsA[buf ^ 1][loff[j]]);
                load16(Wg + k0 + goff[j], &lsB[buf ^ 1][loff[j]]);
            }
            asm volatile("s_waitcnt vmcnt(8)" ::: "memory");
        } else {
            asm volatile("s_waitcnt vmcnt(0)" ::: "memory");
        }
        __builtin_amdgcn_s_barrier();
        __builtin_amdgcn_sched_barrier(0);     // rule #18

        const char* bA = (const char*)lsA[buf];
        const char* bB = (const char*)lsB[buf];
        #pragma unroll
        for (int kk = 0; kk < 4; ++kk) {
            bf16x8 a[4], b[2];
            #pragma unroll
            for (int m = 0; m < 4; ++m)
                a[m] = *(const bf16x8*)(bA + (wr + m * 16 + fr) * 256 + ofs[kk]);
            #pragma unroll
            for (int n = 0; n < 2; ++n)
                b[n] = *(const bf16x8*)(bB + (wc + n * 16 + fr) * 256 + ofs[kk]);
            #pragma unroll
            for (int m = 0; m < 4; ++m)
                #pragma unroll
                for (int n = 0; n < 2; ++n)
                    acc[m][n] = __builtin_amdgcn_mfma_f32_16x16x32_bf16(
                        a[m], b[n], acc[m][n], 0, 0, 0);
        }
        __builtin_amdgcn_s_barrier();
        __builtin_amdgcn_sched_barrier(0);
    }

    f16* Pk = P + kz * 524288;
    const int cr0 = brow + wr + q * 4;
    const int cc0 = bcol + wc + fr;
    #pragma unroll
    for (int m = 0; m < 4; ++m)
        #pragma unroll
        for (int n = 0; n < 2; ++n)
            #pragma unroll
            for (int j = 0; j < 4; ++j)
                Pk[(cr0 + m * 16 + j) * 1024 + cc0 + n * 16] = (f16)acc[m][n][j];
}

// r8 reduce verbatim: fixed-order 8-slice f16 sum -> f32 (deterministic).
__global__ __launch_bounds__(256) void reduce_kernel(
    const f16* __restrict__ P, float* __restrict__ out)
{
    const int idx = (blockIdx.x * 256 + threadIdx.x) * 8;
    float s[8] = {};
    #pragma unroll
    for (int z = 0; z < 8; ++z) {
        f16x8 v = *(const f16x8*)(P + z * 524288 + idx);
        #pragma unroll
        for (int e = 0; e < 8; ++e) s[e] += (float)v[e];
    }
    float4 o0, o1;
    o0.x = s[0]; o0.y = s[1]; o0.z = s[2]; o0.w = s[3];
    o1.x = s[4]; o1.y = s[5]; o1.z = s[6]; o1.w = s[7];
    *(float4*)(out + idx)     = o0;
    *(float4*)(out + idx + 4) = o1;
}

extern "C" void kernel_launch(void* const* d_in, const int* in_sizes, int n_in,
                              void* d_out, int out_size, void* d_ws, size_t ws_size,
                              hipStream_t stream)
{
    const float* x   = (const float*)d_in[0];
    const float* cp0 = (const float*)d_in[1];
    const float* cp1 = (const float*)d_in[2];
    const float* cp2 = (const float*)d_in[3];
    const float* cp3 = (const float*)d_in[4];

    u16*   A   = (u16*)d_ws;
    u16*   Wb  = (u16*)((char*)d_ws + (4u << 20));
    f16*   P   = (f16*)((char*)d_ws + (12u << 20));
    float* out = (float*)d_out;

    prep_kernel<<<640, 256, 0, stream>>>(x, cp0, cp1, cp2, cp3, A, Wb);
    gemm_kernel<<<256, 512, 0, stream>>>(A, Wb, P);
    reduce_kernel<<<256, 256, 0, stream>>>(P, out);
}

// Round 15
// 23.744 us; speedup vs baseline: 2.4330x; 1.0462x over previous
//
#include <hip/hip_runtime.h>

#define AS1 __attribute__((address_space(1)))
#define AS3 __attribute__((address_space(3)))

typedef unsigned short u16;
typedef _Float16 f16;
typedef __bf16 bf16x8 __attribute__((ext_vector_type(8)));
typedef float f32x4 __attribute__((ext_vector_type(4)));
typedef _Float16 f16x8 __attribute__((ext_vector_type(8)));
typedef unsigned short u16x8 __attribute__((ext_vector_type(8)));

// ws layout (20 MB):
//   A: [4][512][1024]  bf16(u16) @ 0      (4 MB)   A[seg][b][i] = b_seg(x[b][i])
//   W: [4][1024][1024] bf16(u16) @ 4 MB   (8 MB)   W[seg][o][i] = bf16(cp_seg[o][i])
//   P: [8][512][1024]  f16       @ 12 MB  (8 MB)   split-K partials (f16)

__device__ __forceinline__ u16 bf(float f) {
    union { __bf16 h; u16 u; } c;
    c.h = (__bf16)f;               // RNE, compiler-optimal cvt (m240)
    return c.u;
}

// r14 prep verbatim: streaming-clean, one block = one contiguous chunk.
__global__ __launch_bounds__(256) void prep_kernel(
    const float* __restrict__ x,
    const float* __restrict__ cp0, const float* __restrict__ cp1,
    const float* __restrict__ cp2, const float* __restrict__ cp3,
    u16* __restrict__ A, u16* __restrict__ W)
{
    const int bid = blockIdx.x;
    const int tid = threadIdx.x;
    if (bid < 512) {
        const int seg  = bid >> 7;
        const int base = (bid & 127) * 8192;
        const float* cps[4] = {cp0, cp1, cp2, cp3};
        const float* src = cps[seg] + base;
        u16* dst = W + seg * 1048576 + base;
        #pragma unroll
        for (int it = 0; it < 4; ++it) {
            const int e = it * 2048 + tid * 8;
            float4 v0 = *(const float4*)(src + e);
            float4 v1 = *(const float4*)(src + e + 4);
            u16x8 o;
            o[0] = bf(v0.x); o[1] = bf(v0.y); o[2] = bf(v0.z); o[3] = bf(v0.w);
            o[4] = bf(v1.x); o[5] = bf(v1.y); o[6] = bf(v1.z); o[7] = bf(v1.w);
            *(u16x8*)(dst + e) = o;
        }
    } else {
        const int base = (bid - 512) * 4096;
        #pragma unroll
        for (int it = 0; it < 2; ++it) {
            const int idx = base + it * 2048 + tid * 8;
            float4 v0 = *(const float4*)(x + idx);
            float4 v1 = *(const float4*)(x + idx + 4);
            float vv[8] = {v0.x, v0.y, v0.z, v0.w, v1.x, v1.y, v1.z, v1.w};
            u16 q[4][8];
            #pragma unroll
            for (int j = 0; j < 8; ++j) {
                float xx = vv[j];
                float t = fminf(fabsf(xx), 1.0f);
                float s = 1.0f - t;
                q[0][j] = bf(s * s * s * xx);
                q[1][j] = bf(3.0f * s * s * t * xx);
                q[2][j] = bf(3.0f * s * t * t * xx);
                q[3][j] = bf(t * t * t * xx);
            }
            #pragma unroll
            for (int seg = 0; seg < 4; ++seg) {
                u16x8 o;
                #pragma unroll
                for (int j = 0; j < 8; ++j) o[j] = q[seg][j];
                *(u16x8*)(A + seg * 524288 + idx) = o;
            }
        }
    }
}

__device__ __forceinline__ void load16(const u16* g, u16* l) {
    __builtin_amdgcn_global_load_lds((const AS1 unsigned int*)g,
                                     (AS3 unsigned int*)l, 16, 0, 0);
}

// 128x128 tile, BK=64, 8 k-steps, split-K=8, 512 threads (8 waves of 64x32).
// 3-DEEP pipeline, ONE barrier per step: DMA for tile t+2 issued at step t
// (~2 steps of latency cover); per-wave s_waitcnt vmcnt(4) retires only its
// own tile-t loads; queue never drains until the tail (T3/T4).
// LDS 3 bufs x (16+16) KB = 96 KB. XOR swizzle: chunk (row,s) holds global
// (row, s^(row&7)); pre-swizzled source, linear LDS dest (rule #21).
__global__ __launch_bounds__(512) void gemm_kernel(
    const u16* __restrict__ A, const u16* __restrict__ W,
    f16* __restrict__ P)
{
    __shared__ u16 lsA[3][128 * 64];
    __shared__ u16 lsB[3][128 * 64];

    const int tid  = threadIdx.x;
    const int lane = tid & 63;
    const int wid  = tid >> 6;

    const int bid  = blockIdx.x;          // 0..255
    const int grp  = bid & 7;             // XCD group = (mb>>1)*4 + (nb>>1)
    const int sub  = bid >> 3;            // 0..31 within group
    const int mb   = (grp >> 2) * 2 + (sub & 1);
    const int nb   = (grp & 3) * 2 + ((sub >> 1) & 1);
    const int kz   = sub >> 2;            // 0..7
    const int seg  = kz >> 1;
    const int kbase = (kz & 1) * 512;
    const int brow = mb * 128;
    const int bcol = nb * 128;

    const u16* Ag = A + seg * 524288  + brow * 1024 + kbase;
    const u16* Wg = W + seg * 1048576 + bcol * 1024 + kbase;

    // staging: 1024 chunks of 16B per tile (128 rows x 8 chunks); 2/thread/matrix
    int goff[2], loff[2];
    #pragma unroll
    for (int j = 0; j < 2; ++j) {
        const int c   = tid + j * 512;
        const int row = c >> 3;
        goff[j] = row * 1024 + ((c & 7) ^ (row & 7)) * 8;
        loff[j] = c * 8;
    }

    // wave sub-tile: 2(M) x 4(N); each wave 64x32
    const int wr = (wid >> 2) * 64;
    const int wc = (wid & 3) * 32;
    const int fr = lane & 15;
    const int q  = lane >> 4;
    int ofs[2];
    ofs[0] = ((q    ) ^ (lane & 7)) * 16;
    ofs[1] = ((q + 4) ^ (lane & 7)) * 16;

    f32x4 acc[4][2] = {};

    // ---- prologue: issue tiles 0,1 (8 loads/thread outstanding) ----
    #pragma unroll
    for (int j = 0; j < 2; ++j) {
        load16(Ag + goff[j],      &lsA[0][loff[j]]);
        load16(Wg + goff[j],      &lsB[0][loff[j]]);
    }
    #pragma unroll
    for (int j = 0; j < 2; ++j) {
        load16(Ag + 64 + goff[j], &lsA[1][loff[j]]);
        load16(Wg + 64 + goff[j], &lsB[1][loff[j]]);
    }

    #pragma unroll
    for (int kt = 0; kt < 8; ++kt) {
        const int buf = kt % 3;
        // own tile-kt loads retired (oldest 4); tile kt+1's 4 stay in flight
        if (kt < 7) {
            asm volatile("s_waitcnt vmcnt(4)" ::: "memory");
        } else {
            asm volatile("s_waitcnt vmcnt(0)" ::: "memory");
        }
        __builtin_amdgcn_s_barrier();          // all waves: buf ready, and all
        __builtin_amdgcn_sched_barrier(0);     // finished step kt-1 (rule #18)

        if (kt < 6) {
            const int k0 = (kt + 2) * 64;
            const int nbuf = (kt + 2) % 3;     // == buf consumed at step kt-1
            #pragma unroll
            for (int j = 0; j < 2; ++j) {
                load16(Ag + k0 + goff[j], &lsA[nbuf][loff[j]]);
                load16(Wg + k0 + goff[j], &lsB[nbuf][loff[j]]);
            }
        }

        const char* bA = (const char*)lsA[buf];
        const char* bB = (const char*)lsB[buf];
        #pragma unroll
        for (int kk = 0; kk < 2; ++kk) {
            bf16x8 a[4], b[2];
            #pragma unroll
            for (int m = 0; m < 4; ++m)
                a[m] = *(const bf16x8*)(bA + (wr + m * 16 + fr) * 128 + ofs[kk]);
            #pragma unroll
            for (int n = 0; n < 2; ++n)
                b[n] = *(const bf16x8*)(bB + (wc + n * 16 + fr) * 128 + ofs[kk]);
            #pragma unroll
            for (int m = 0; m < 4; ++m)
                #pragma unroll
                for (int n = 0; n < 2; ++n)
                    acc[m][n] = __builtin_amdgcn_mfma_f32_16x16x32_bf16(
                        a[m], b[n], acc[m][n], 0, 0, 0);
        }
    }

    // ---- epilogue: f16 partials. C/D layout col=lane&15, row=(lane>>4)*4+j ----
    f16* Pk = P + kz * 524288;
    const int cr0 = brow + wr + q * 4;
    const int cc0 = bcol + wc + fr;
    #pragma unroll
    for (int m = 0; m < 4; ++m)
        #pragma unroll
        for (int n = 0; n < 2; ++n)
            #pragma unroll
            for (int j = 0; j < 4; ++j)
                Pk[(cr0 + m * 16 + j) * 1024 + cc0 + n * 16] = (f16)acc[m][n][j];
}

// r8 reduce verbatim: fixed-order 8-slice f16 sum -> f32 (deterministic).
__global__ __launch_bounds__(256) void reduce_kernel(
    const f16* __restrict__ P, float* __restrict__ out)
{
    const int idx = (blockIdx.x * 256 + threadIdx.x) * 8;
    float s[8] = {};
    #pragma unroll
    for (int z = 0; z < 8; ++z) {
        f16x8 v = *(const f16x8*)(P + z * 524288 + idx);
        #pragma unroll
        for (int e = 0; e < 8; ++e) s[e] += (float)v[e];
    }
    float4 o0, o1;
    o0.x = s[0]; o0.y = s[1]; o0.z = s[2]; o0.w = s[3];
    o1.x = s[4]; o1.y = s[5]; o1.z = s[6]; o1.w = s[7];
    *(float4*)(out + idx)     = o0;
    *(float4*)(out + idx + 4) = o1;
}

extern "C" void kernel_launch(void* const* d_in, const int* in_sizes, int n_in,
                              void* d_out, int out_size, void* d_ws, size_t ws_size,
                              hipStream_t stream)
{
    const float* x   = (const float*)d_in[0];
    const float* cp0 = (const float*)d_in[1];
    const float* cp1 = (const float*)d_in[2];
    const float* cp2 = (const float*)d_in[3];
    const float* cp3 = (const float*)d_in[4];

    u16*   A   = (u16*)d_ws;
    u16*   Wb  = (u16*)((char*)d_ws + (4u << 20));
    f16*   P   = (f16*)((char*)d_ws + (12u << 20));
    float* out = (float*)d_out;

    prep_kernel<<<640, 256, 0, stream>>>(x, cp0, cp1, cp2, cp3, A, Wb);
    gemm_kernel<<<256, 512, 0, stream>>>(A, Wb, P);
    reduce_kernel<<<256, 256, 0, stream>>>(P, out);
}